// Round 12
// baseline (761.962 us; speedup 1.0000x reference)
//
#include <hip/hip_runtime.h>
#include <hip/hip_bf16.h>
#include <stdint.h>

#define M_TOT 8192
#define N_TOT 16384
#define K_TOT 4096

typedef int v4i __attribute__((ext_vector_type(4)));
typedef int v16i __attribute__((ext_vector_type(16)));

__device__ __forceinline__ float fix_scale(float s) { return s == 0.0f ? 1.0f : s; }

__device__ __forceinline__ void gload_lds16(const void* g, void* l) {
    __builtin_amdgcn_global_load_lds((__attribute__((address_space(1))) void*)g,
                                     (__attribute__((address_space(3))) void*)l,
                                     16, 0, 0);
}

__device__ __forceinline__ int8_t quant1(float x, float scale) {
    float r = fminf(127.0f, fmaxf(-127.0f, rintf(x / scale)));
    return (int8_t)(int)r;
}

__device__ __forceinline__ unsigned pack4(float4 v, float scale) {
    unsigned b0 = (unsigned char)quant1(v.x, scale);
    unsigned b1 = (unsigned char)quant1(v.y, scale);
    unsigned b2 = (unsigned char)quant1(v.z, scale);
    unsigned b3 = (unsigned char)quant1(v.w, scale);
    return b0 | (b1 << 8) | (b2 << 16) | (b3 << 24);
}

// Tiled fragment-major operand layout (16 KB chunks per (tile,kt)):
//   granule g = (frag*2 + s)*64 + h*32 + r  holds  row/col = tile*256 + frag*32 + r,
//   k-bytes kt*64 + s*32 + h*16 .. +15.
// GEMM fragment read = contiguous 1 KB per wave (bank-conflict-free);
// GEMM staging = contiguous 16 KB chunk copies (ideal coalescing).

// ---------------- lhs: per-row absmax quantize -> tiled qA_t ----------------
__global__ __launch_bounds__(256) void k_quant_lhs(const float* __restrict__ x,
                                                   int8_t* __restrict__ qt,
                                                   float* __restrict__ s) {
    const int row = blockIdx.x;
    const int t = threadIdx.x;
    const float4* xr = (const float4*)(x + (size_t)row * K_TOT);
    float4 v[4];
    float m = 0.0f;
#pragma unroll
    for (int i = 0; i < 4; ++i) {
        v[i] = xr[t * 4 + i];   // thread owns k-elems 16t .. 16t+15
        m = fmaxf(m, fmaxf(fmaxf(fabsf(v[i].x), fabsf(v[i].y)),
                           fmaxf(fabsf(v[i].z), fabsf(v[i].w))));
    }
#pragma unroll
    for (int off = 32; off; off >>= 1) m = fmaxf(m, __shfl_xor(m, off));
    __shared__ float wmax[4];
    if ((t & 63) == 0) wmax[t >> 6] = m;
    __syncthreads();
    m = fmaxf(fmaxf(wmax[0], wmax[1]), fmaxf(wmax[2], wmax[3]));
    const float scale = fix_scale(m / 127.0f);
    if (t == 0) s[row] = scale;

    v4i w;
#pragma unroll
    for (int i = 0; i < 4; ++i) w[i] = (int)pack4(v[i], scale);

    const int mt = row >> 8, mb = (row >> 5) & 7, r = row & 31;
    const int kt = t >> 2, s2 = (t >> 1) & 1, h = t & 1;
    const size_t gidx = (size_t)(mt * 64 + kt) * 1024 + (size_t)((mb * 2 + s2) * 64 + h * 32 + r);
    ((v4i*)qt)[gidx] = w;
}

// ---------------- rhs: per-column absmax (atomicMax on float bits) ----------------
__global__ __launch_bounds__(256) void k_rhs_absmax(const float* __restrict__ rhs,
                                                    unsigned* __restrict__ amax) {
    const int f = blockIdx.x * 256 + threadIdx.x;
    const int d0 = blockIdx.y * 256;
    const float* p = rhs + (size_t)d0 * N_TOT + f;
    float m = 0.0f;
#pragma unroll 4
    for (int d = 0; d < 256; ++d)
        m = fmaxf(m, fabsf(p[(size_t)d * N_TOT]));
    atomicMax(amax + f, __float_as_uint(m));
}

__global__ __launch_bounds__(256) void k_rhs_scale(const unsigned* __restrict__ amax,
                                                   float* __restrict__ s) {
    const int f = blockIdx.x * 256 + threadIdx.x;
    s[f] = fix_scale(__uint_as_float(amax[f]) / 127.0f);
}

// ---------------- rhs: quantize + transpose -> tiled qB_t (256-col tiles) ----------------
__global__ __launch_bounds__(256) void k_quant_rhs_t(const float* __restrict__ rhs,
                                                     const float* __restrict__ s,
                                                     int8_t* __restrict__ qt) {
    const int f0 = blockIdx.x * 64;   // col base (multiple of 64)
    const int d0 = blockIdx.y * 64;   // k base
    const int t = threadIdx.x;
    __shared__ float sc[64];
    __shared__ alignas(16) int8_t tile[64][64];  // [col local][k local]
    if (t < 64) sc[t] = s[f0 + t];
    __syncthreads();
    const int fl = (t & 15) * 4;
    const int rl = t >> 4;
#pragma unroll
    for (int i = 0; i < 4; ++i) {
        const int dl = i * 16 + rl;
        float4 v = *(const float4*)(rhs + (size_t)(d0 + dl) * N_TOT + f0 + fl);
        tile[fl + 0][dl] = quant1(v.x, sc[fl + 0]);
        tile[fl + 1][dl] = quant1(v.y, sc[fl + 1]);
        tile[fl + 2][dl] = quant1(v.z, sc[fl + 2]);
        tile[fl + 3][dl] = quant1(v.w, sc[fl + 3]);
    }
    __syncthreads();
    // one 16B granule per thread, tiled-layout ordering (BN tile = 256 cols)
    const int nb_l = t >> 7, s2 = (t >> 6) & 1, h = (t >> 5) & 1, r = t & 31;
    const int col_local = nb_l * 32 + r;
    const int kb16 = s2 * 2 + h;
    const int nt = f0 >> 8;                      // 256-col tile index
    const int nb = ((f0 >> 5) & 7) + nb_l;       // 32-col frag within tile
    const int kt = d0 >> 6;
    const size_t gidx = (size_t)(nt * 64 + kt) * 1024 + (size_t)((nb * 2 + s2) * 64 + h * 32 + r);
    ((v4i*)qt)[gidx] = *(const v4i*)&tile[col_local][kb16 * 16];
}

// ---- int8 GEMM: 256x256, 8 waves of 128x64 (32x32x32), reg-prefetch pipelined ----
#define BM 256
#define BN 256
#define BK 64
#define NKT (K_TOT / BK)   // 64

#define MFMA_I8(A, B, Cc) __builtin_amdgcn_mfma_i32_32x32x32_i8((A), (B), (Cc), 0, 0, 0)

struct Frags {
    v4i a0[4], a1[4];   // A frags, slice 0 / slice 1
    v4i b0[2], b1[2];   // B frags, slice 0 / slice 1
};

__global__ __launch_bounds__(512, 2) void k_gemm(const int8_t* __restrict__ qA,   // tiled
                                                 const int8_t* __restrict__ qB,   // tiled
                                                 const float* __restrict__ sA,
                                                 const float* __restrict__ sB,
                                                 float* __restrict__ C) {
    // 4-deep buffer (stage kt+3 ahead): per K-tile chunk = A 16KB + B 16KB
    __shared__ alignas(1024) int8_t lds[4][32768];   // 128 KB -> 1 block/CU

    // supercolumn raster: 2 bn-tiles wide (verified FETCH ~394 MB)
    const int bid = blockIdx.x;          // 0..2047
    const int scc = bid >> 6;            // 32 supercolumns
    const int ii = bid & 63;
    const int mt = ii & 31;
    const int ntile = (scc << 1) | (ii >> 5);
    const int bm0 = mt << 8;
    const int bn0 = ntile << 8;

    const int tid = threadIdx.x;         // 0..511
    const int wave = tid >> 6;
    const int lane = tid & 63;
    const int wm = (wave >> 2) * 128;    // 2 wave-rows
    const int wn = (wave & 3) * 64;      // 4 wave-cols

    const int8_t* aBase = qA + (size_t)mt * (64 * 16384);
    const int8_t* bBase = qB + (size_t)ntile * (64 * 16384);

    // fragment offsets (lane-contiguous 1KB): A frag f slice s: aoff + f*2048 + s*1024
    const int aoff = (wave >> 2) * 8192 + lane * 16;
    const int boff = 16384 + (wave & 3) * 4096 + lane * 16;   // + n*2048 + s*1024

    v16i acc[4][2];
#pragma unroll
    for (int f = 0; f < 4; ++f)
#pragma unroll
        for (int n = 0; n < 2; ++n)
#pragma unroll
            for (int e = 0; e < 16; ++e) acc[f][n][e] = 0;

    // stage one kt chunk (4 half-tiles, 1 gload/thread each)
    auto stage_kt = [&](int kt) {
        const int b = kt & 3;
#pragma unroll
        for (int h = 0; h < 4; ++h) {
            const int loff = h * 8192 + tid * 16;
            const int8_t* src = (h < 2) ? (aBase + (size_t)kt * 16384 + h * 8192 + tid * 16)
                                        : (bBase + (size_t)kt * 16384 + (h - 2) * 8192 + tid * 16);
            gload_lds16(src, &lds[b][loff]);
        }
    };

    // prologue: stage kt=0,1,2 (12 loads); drain 0,1 (keep kt2's 4 in flight)
    stage_kt(0); stage_kt(1); stage_kt(2);
    asm volatile("s_waitcnt vmcnt(4)" ::: "memory");
    __builtin_amdgcn_s_barrier();

    Frags F0, F1;
    {   // read frags(0) from buf0
        const int8_t* nb = &lds[0][0];
#pragma unroll
        for (int f = 0; f < 4; ++f) {
            F0.a0[f] = *(const v4i*)(nb + aoff + f * 2048);
            F0.a1[f] = *(const v4i*)(nb + aoff + f * 2048 + 1024);
        }
#pragma unroll
        for (int n = 0; n < 2; ++n) {
            F0.b0[n] = *(const v4i*)(nb + boff + n * 2048);
            F0.b1[n] = *(const v4i*)(nb + boff + n * 2048 + 1024);
        }
    }

    auto body = [&](int kt, Frags& cur, Frags& nxt) {
        const bool rd = (kt + 1 < NKT);
        const bool st = (kt + 3 < NKT);
        const int8_t* nb = &lds[(kt + 1) & 3][0];

        // ---- segment 1: issue nxt slice0 reads + stage gloads ----
        if (rd) {
#pragma unroll
            for (int f = 0; f < 4; ++f) nxt.a0[f] = *(const v4i*)(nb + aoff + f * 2048);
#pragma unroll
            for (int n = 0; n < 2; ++n) nxt.b0[n] = *(const v4i*)(nb + boff + n * 2048);
        }
        if (st) stage_kt(kt + 3);
        __builtin_amdgcn_sched_barrier(0);

        // ---- segment 2: MFMA slice0 (overlaps segment-1 reads) ----
        __builtin_amdgcn_s_setprio(1);
#pragma unroll
        for (int f = 0; f < 4; ++f) {
            acc[f][0] = MFMA_I8(cur.a0[f], cur.b0[0], acc[f][0]);
            acc[f][1] = MFMA_I8(cur.a0[f], cur.b0[1], acc[f][1]);
        }
        __builtin_amdgcn_s_setprio(0);

        // ---- segment 3: issue nxt slice1 reads ----
        if (rd) {
#pragma unroll
            for (int f = 0; f < 4; ++f) nxt.a1[f] = *(const v4i*)(nb + aoff + f * 2048 + 1024);
#pragma unroll
            for (int n = 0; n < 2; ++n) nxt.b1[n] = *(const v4i*)(nb + boff + n * 2048 + 1024);
        }
        __builtin_amdgcn_sched_barrier(0);

        // ---- segment 4: MFMA slice1 (overlaps segment-3 reads) ----
        __builtin_amdgcn_s_setprio(1);
#pragma unroll
        for (int f = 0; f < 4; ++f) {
            acc[f][0] = MFMA_I8(cur.a1[f], cur.b1[0], acc[f][0]);
            acc[f][1] = MFMA_I8(cur.a1[f], cur.b1[1], acc[f][1]);
        }
        __builtin_amdgcn_s_setprio(0);

        // ---- tail: waits + single barrier per kt ----
        if (rd) {
            asm volatile("s_waitcnt lgkmcnt(0)" ::: "memory");
            if (st)                asm volatile("s_waitcnt vmcnt(4)" ::: "memory");
            else if (kt + 2 < NKT) asm volatile("s_waitcnt vmcnt(0)" ::: "memory");
            __builtin_amdgcn_s_barrier();
        }
    };

    for (int kt = 0; kt < NKT; kt += 2) {
        body(kt, F0, F1);
        body(kt + 1, F1, F0);
    }

    // epilogue: dequant + store. 32x32 C/D: col = lane&31, row = (r&3)+8*(r>>2)+4*(lane>>5)
    const int cc0 = lane & 31;
    const int rbase = (lane >> 5) * 4;
#pragma unroll
    for (int f = 0; f < 4; ++f) {
#pragma unroll
        for (int r = 0; r < 16; ++r) {
            const int gr = bm0 + wm + f * 32 + (r & 3) + 8 * (r >> 2) + rbase;
            const float sa = sA[gr];
            float* crow = C + (size_t)gr * N_TOT + bn0 + wn;
#pragma unroll
            for (int n = 0; n < 2; ++n)
                crow[n * 32 + cc0] = (float)acc[f][n][r] * sa * sB[bn0 + wn + n * 32 + cc0];
        }
    }
}

extern "C" void kernel_launch(void* const* d_in, const int* in_sizes, int n_in,
                              void* d_out, int out_size, void* d_ws, size_t ws_size,
                              hipStream_t stream) {
    const float* lhs = (const float*)d_in[0];
    const float* rhs = (const float*)d_in[1];
    float* out = (float*)d_out;
    char* ws = (char*)d_ws;

    int8_t* qA = (int8_t*)ws;                                   // 32 MB (tiled)
    int8_t* qB = (int8_t*)(ws + (size_t)33554432);              // 64 MB (tiled)
    float* sA = (float*)(ws + (size_t)33554432 + 67108864);     // 32 KB
    float* sB = sA + M_TOT;                                     // 64 KB
    unsigned* amax = (unsigned*)(sB + N_TOT);                   // 64 KB

    hipMemsetAsync(amax, 0, N_TOT * sizeof(unsigned), stream);

    k_quant_lhs<<<M_TOT, 256, 0, stream>>>(lhs, qA, sA);
    k_rhs_absmax<<<dim3(N_TOT / 256, K_TOT / 256), 256, 0, stream>>>(rhs, amax);
    k_rhs_scale<<<N_TOT / 256, 256, 0, stream>>>(amax, sB);
    k_quant_rhs_t<<<dim3(N_TOT / 64, K_TOT / 64), 256, 0, stream>>>(rhs, sB, qB);
    k_gemm<<<(M_TOT / BM) * (N_TOT / BN), 512, 0, stream>>>(qA, qB, sA, sB, out);
}

// Round 13
// 751.235 us; speedup vs baseline: 1.0143x; 1.0143x over previous
//
#include <hip/hip_runtime.h>
#include <hip/hip_bf16.h>
#include <stdint.h>

#define M_TOT 8192
#define N_TOT 16384
#define K_TOT 4096

typedef int v4i __attribute__((ext_vector_type(4)));
typedef int v16i __attribute__((ext_vector_type(16)));

__device__ __forceinline__ float fix_scale(float s) { return s == 0.0f ? 1.0f : s; }

__device__ __forceinline__ void gload_lds16(const void* g, void* l) {
    __builtin_amdgcn_global_load_lds((__attribute__((address_space(1))) void*)g,
                                     (__attribute__((address_space(3))) void*)l,
                                     16, 0, 0);
}

__device__ __forceinline__ int8_t quant1(float x, float scale) {
    float r = fminf(127.0f, fmaxf(-127.0f, rintf(x / scale)));
    return (int8_t)(int)r;
}

__device__ __forceinline__ unsigned pack4(float4 v, float scale) {
    unsigned b0 = (unsigned char)quant1(v.x, scale);
    unsigned b1 = (unsigned char)quant1(v.y, scale);
    unsigned b2 = (unsigned char)quant1(v.z, scale);
    unsigned b3 = (unsigned char)quant1(v.w, scale);
    return b0 | (b1 << 8) | (b2 << 16) | (b3 << 24);
}

// Tiled fragment-major operand layout (16 KB chunks per (tile,kt)):
//   granule g = (frag*2 + s)*64 + h*32 + r  holds  row/col = tile*256 + frag*32 + r,
//   k-bytes kt*64 + s*32 + h*16 .. +15.
// GEMM fragment read = contiguous 1 KB per wave (bank-conflict-free);
// GEMM staging = contiguous 16 KB chunk copies (ideal coalescing).

// ---------------- lhs: per-row absmax quantize -> tiled qA_t ----------------
__global__ __launch_bounds__(256) void k_quant_lhs(const float* __restrict__ x,
                                                   int8_t* __restrict__ qt,
                                                   float* __restrict__ s) {
    const int row = blockIdx.x;
    const int t = threadIdx.x;
    const float4* xr = (const float4*)(x + (size_t)row * K_TOT);
    float4 v[4];
    float m = 0.0f;
#pragma unroll
    for (int i = 0; i < 4; ++i) {
        v[i] = xr[t * 4 + i];   // thread owns k-elems 16t .. 16t+15
        m = fmaxf(m, fmaxf(fmaxf(fabsf(v[i].x), fabsf(v[i].y)),
                           fmaxf(fabsf(v[i].z), fabsf(v[i].w))));
    }
#pragma unroll
    for (int off = 32; off; off >>= 1) m = fmaxf(m, __shfl_xor(m, off));
    __shared__ float wmax[4];
    if ((t & 63) == 0) wmax[t >> 6] = m;
    __syncthreads();
    m = fmaxf(fmaxf(wmax[0], wmax[1]), fmaxf(wmax[2], wmax[3]));
    const float scale = fix_scale(m / 127.0f);
    if (t == 0) s[row] = scale;

    v4i w;
#pragma unroll
    for (int i = 0; i < 4; ++i) w[i] = (int)pack4(v[i], scale);

    const int mt = row >> 8, mb = (row >> 5) & 7, r = row & 31;
    const int kt = t >> 2, s2 = (t >> 1) & 1, h = t & 1;
    const size_t gidx = (size_t)(mt * 64 + kt) * 1024 + (size_t)((mb * 2 + s2) * 64 + h * 32 + r);
    ((v4i*)qt)[gidx] = w;
}

// ---------------- rhs: per-column absmax (atomicMax on float bits) ----------------
__global__ __launch_bounds__(256) void k_rhs_absmax(const float* __restrict__ rhs,
                                                    unsigned* __restrict__ amax) {
    const int f = blockIdx.x * 256 + threadIdx.x;
    const int d0 = blockIdx.y * 256;
    const float* p = rhs + (size_t)d0 * N_TOT + f;
    float m = 0.0f;
#pragma unroll 4
    for (int d = 0; d < 256; ++d)
        m = fmaxf(m, fabsf(p[(size_t)d * N_TOT]));
    atomicMax(amax + f, __float_as_uint(m));
}

__global__ __launch_bounds__(256) void k_rhs_scale(const unsigned* __restrict__ amax,
                                                   float* __restrict__ s) {
    const int f = blockIdx.x * 256 + threadIdx.x;
    s[f] = fix_scale(__uint_as_float(amax[f]) / 127.0f);
}

// ---------------- rhs: quantize + transpose -> tiled qB_t (256-col tiles) ----------------
__global__ __launch_bounds__(256) void k_quant_rhs_t(const float* __restrict__ rhs,
                                                     const float* __restrict__ s,
                                                     int8_t* __restrict__ qt) {
    const int f0 = blockIdx.x * 64;   // col base (multiple of 64)
    const int d0 = blockIdx.y * 64;   // k base
    const int t = threadIdx.x;
    __shared__ float sc[64];
    __shared__ alignas(16) int8_t tile[64][64];  // [col local][k local]
    if (t < 64) sc[t] = s[f0 + t];
    __syncthreads();
    const int fl = (t & 15) * 4;
    const int rl = t >> 4;
#pragma unroll
    for (int i = 0; i < 4; ++i) {
        const int dl = i * 16 + rl;
        float4 v = *(const float4*)(rhs + (size_t)(d0 + dl) * N_TOT + f0 + fl);
        tile[fl + 0][dl] = quant1(v.x, sc[fl + 0]);
        tile[fl + 1][dl] = quant1(v.y, sc[fl + 1]);
        tile[fl + 2][dl] = quant1(v.z, sc[fl + 2]);
        tile[fl + 3][dl] = quant1(v.w, sc[fl + 3]);
    }
    __syncthreads();
    // one 16B granule per thread, tiled-layout ordering (BN tile = 256 cols)
    const int nb_l = t >> 7, s2 = (t >> 6) & 1, h = (t >> 5) & 1, r = t & 31;
    const int col_local = nb_l * 32 + r;
    const int kb16 = s2 * 2 + h;
    const int nt = f0 >> 8;                      // 256-col tile index
    const int nb = ((f0 >> 5) & 7) + nb_l;       // 32-col frag within tile
    const int kt = d0 >> 6;
    const size_t gidx = (size_t)(nt * 64 + kt) * 1024 + (size_t)((nb * 2 + s2) * 64 + h * 32 + r);
    ((v4i*)qt)[gidx] = *(const v4i*)&tile[col_local][kb16 * 16];
}

// ---- int8 GEMM: 256x256 tile, 4 waves of 128x128 (32x32x32), min-LDS-traffic ----
#define BM 256
#define BN 256
#define BK 64
#define NKT (K_TOT / BK)   // 64

#define MFMA_I8(A, B, Cc) __builtin_amdgcn_mfma_i32_32x32x32_i8((A), (B), (Cc), 0, 0, 0)

__global__ __launch_bounds__(256, 1) void k_gemm(const int8_t* __restrict__ qA,   // tiled
                                                 const int8_t* __restrict__ qB,   // tiled
                                                 const float* __restrict__ sA,
                                                 const float* __restrict__ sB,
                                                 float* __restrict__ C) {
    // 3-deep buffer: per K-tile chunk = A 16KB + B 16KB
    __shared__ alignas(1024) int8_t lds[3][32768];   // 96 KB

    // supercolumn raster: 2 bn-tiles wide (verified FETCH ~394 MB)
    const int bid = blockIdx.x;          // 0..2047
    const int scc = bid >> 6;            // 32 supercolumns
    const int ii = bid & 63;
    const int mt = ii & 31;
    const int ntile = (scc << 1) | (ii >> 5);
    const int bm0 = mt << 8;
    const int bn0 = ntile << 8;

    const int tid = threadIdx.x;         // 0..255
    const int wave = tid >> 6;
    const int lane = tid & 63;
    const int wm = (wave >> 1) * 128;    // 2 wave-rows
    const int wn = (wave & 1) * 128;     // 2 wave-cols

    const int8_t* aBase = qA + (size_t)mt * (64 * 16384);
    const int8_t* bBase = qB + (size_t)ntile * (64 * 16384);

    // fragment offsets (lane-contiguous 1KB): A frag f slice s: aoff + f*2048 + s*1024
    const int aoff = (wave >> 1) * 8192 + lane * 16;
    const int boff = 16384 + (wave & 1) * 8192 + lane * 16;

    v16i acc[4][4];
#pragma unroll
    for (int f = 0; f < 4; ++f)
#pragma unroll
        for (int n = 0; n < 4; ++n)
#pragma unroll
            for (int e = 0; e < 16; ++e) acc[f][n][e] = 0;

    // stage half a kt chunk (half=0 -> A 16KB, half=1 -> B 16KB): 4 gloads/thread
    auto stage_half = [&](int kt, int half) {
        const int b = kt % 3;
        const int8_t* src = (half == 0) ? (aBase + (size_t)kt * 16384)
                                        : (bBase + (size_t)kt * 16384);
        const int loff = half * 16384;
#pragma unroll
        for (int h = 0; h < 4; ++h)
            gload_lds16(src + h * 4096 + tid * 16, &lds[b][loff + h * 4096 + tid * 16]);
    };

    // prologue: stage kt=0,1 fully (16 loads); wait kt0's 8, keep kt1's in flight
    stage_half(0, 0); stage_half(0, 1);
    stage_half(1, 0); stage_half(1, 1);
    asm volatile("s_waitcnt vmcnt(8)" ::: "memory");
    __builtin_amdgcn_s_barrier();

    for (int kt = 0; kt < NKT; ++kt) {
        const int8_t* a = &lds[kt % 3][0];
        const bool st = (kt + 2 < NKT);
        v4i af[4], bf[4];

        // ======== phase 0: slice 0 (A f0-3 + B n0-3), stage A(kt+2) ========
        af[0] = *(const v4i*)(a + aoff + 0 * 2048);
        af[1] = *(const v4i*)(a + aoff + 1 * 2048);
        af[2] = *(const v4i*)(a + aoff + 2 * 2048);
        af[3] = *(const v4i*)(a + aoff + 3 * 2048);
        bf[0] = *(const v4i*)(a + boff + 0 * 2048);
        bf[1] = *(const v4i*)(a + boff + 1 * 2048);
        bf[2] = *(const v4i*)(a + boff + 2 * 2048);
        bf[3] = *(const v4i*)(a + boff + 3 * 2048);
        if (st) stage_half(kt + 2, 0);
        __builtin_amdgcn_s_barrier();
        asm volatile("s_waitcnt lgkmcnt(0)" ::: "memory");
        __builtin_amdgcn_s_setprio(1);
#pragma unroll
        for (int f = 0; f < 4; ++f) {
            acc[f][0] = MFMA_I8(af[f], bf[0], acc[f][0]);
            acc[f][1] = MFMA_I8(af[f], bf[1], acc[f][1]);
            acc[f][2] = MFMA_I8(af[f], bf[2], acc[f][2]);
            acc[f][3] = MFMA_I8(af[f], bf[3], acc[f][3]);
        }
        __builtin_amdgcn_s_setprio(0);
        __builtin_amdgcn_s_barrier();

        // ======== phase 1: slice 1 (A f0-3 + B n0-3), stage B(kt+2) ========
        af[0] = *(const v4i*)(a + aoff + 0 * 2048 + 1024);
        af[1] = *(const v4i*)(a + aoff + 1 * 2048 + 1024);
        af[2] = *(const v4i*)(a + aoff + 2 * 2048 + 1024);
        af[3] = *(const v4i*)(a + aoff + 3 * 2048 + 1024);
        bf[0] = *(const v4i*)(a + boff + 0 * 2048 + 1024);
        bf[1] = *(const v4i*)(a + boff + 1 * 2048 + 1024);
        bf[2] = *(const v4i*)(a + boff + 2 * 2048 + 1024);
        bf[3] = *(const v4i*)(a + boff + 3 * 2048 + 1024);
        if (st) stage_half(kt + 2, 1);
        __builtin_amdgcn_s_barrier();
        asm volatile("s_waitcnt lgkmcnt(0)" ::: "memory");
        __builtin_amdgcn_s_setprio(1);
#pragma unroll
        for (int f = 0; f < 4; ++f) {
            acc[f][0] = MFMA_I8(af[f], bf[0], acc[f][0]);
            acc[f][1] = MFMA_I8(af[f], bf[1], acc[f][1]);
            acc[f][2] = MFMA_I8(af[f], bf[2], acc[f][2]);
            acc[f][3] = MFMA_I8(af[f], bf[3], acc[f][3]);
        }
        __builtin_amdgcn_s_setprio(0);
        // counted vmcnt once per kt (never 0 in steady state):
        // after this barrier kt+1's 8 loads are complete; kt+2's 8 stay in flight.
        if (kt + 2 < NKT)      asm volatile("s_waitcnt vmcnt(8)" ::: "memory");
        else if (kt + 1 < NKT) asm volatile("s_waitcnt vmcnt(0)" ::: "memory");
        __builtin_amdgcn_s_barrier();
    }

    // epilogue: dequant + store. 32x32 C/D: col = lane&31, row = (r&3)+8*(r>>2)+4*(lane>>5)
    const int cc0 = lane & 31;
    const int rbase = (lane >> 5) * 4;
#pragma unroll
    for (int f = 0; f < 4; ++f) {
#pragma unroll
        for (int r = 0; r < 16; ++r) {
            const int gr = bm0 + wm + f * 32 + (r & 3) + 8 * (r >> 2) + rbase;
            const float sa = sA[gr];
            float* crow = C + (size_t)gr * N_TOT + bn0 + wn;
#pragma unroll
            for (int n = 0; n < 4; ++n)
                crow[n * 32 + cc0] = (float)acc[f][n][r] * sa * sB[bn0 + wn + n * 32 + cc0];
        }
    }
}

extern "C" void kernel_launch(void* const* d_in, const int* in_sizes, int n_in,
                              void* d_out, int out_size, void* d_ws, size_t ws_size,
                              hipStream_t stream) {
    const float* lhs = (const float*)d_in[0];
    const float* rhs = (const float*)d_in[1];
    float* out = (float*)d_out;
    char* ws = (char*)d_ws;

    int8_t* qA = (int8_t*)ws;                                   // 32 MB (tiled)
    int8_t* qB = (int8_t*)(ws + (size_t)33554432);              // 64 MB (tiled)
    float* sA = (float*)(ws + (size_t)33554432 + 67108864);     // 32 KB
    float* sB = sA + M_TOT;                                     // 64 KB
    unsigned* amax = (unsigned*)(sB + N_TOT);                   // 64 KB

    hipMemsetAsync(amax, 0, N_TOT * sizeof(unsigned), stream);

    k_quant_lhs<<<M_TOT, 256, 0, stream>>>(lhs, qA, sA);
    k_rhs_absmax<<<dim3(N_TOT / 256, K_TOT / 256), 256, 0, stream>>>(rhs, amax);
    k_rhs_scale<<<N_TOT / 256, 256, 0, stream>>>(amax, sB);
    k_quant_rhs_t<<<dim3(N_TOT / 64, K_TOT / 64), 256, 0, stream>>>(rhs, sB, qB);
    k_gemm<<<(M_TOT / BM) * (N_TOT / BN), 256, 0, stream>>>(qA, qB, sA, sB, out);
}

// Round 14
// 737.426 us; speedup vs baseline: 1.0333x; 1.0187x over previous
//
#include <hip/hip_runtime.h>
#include <hip/hip_bf16.h>
#include <stdint.h>

#define M_TOT 8192
#define N_TOT 16384
#define K_TOT 4096

typedef int v4i __attribute__((ext_vector_type(4)));

__device__ __forceinline__ float fix_scale(float s) { return s == 0.0f ? 1.0f : s; }

__device__ __forceinline__ void gload_lds16(const void* g, void* l) {
    __builtin_amdgcn_global_load_lds((__attribute__((address_space(1))) void*)g,
                                     (__attribute__((address_space(3))) void*)l,
                                     16, 0, 0);
}

__device__ __forceinline__ int8_t quant1(float x, float scale) {
    float r = fminf(127.0f, fmaxf(-127.0f, rintf(x / scale)));
    return (int8_t)(int)r;
}

__device__ __forceinline__ unsigned pack4(float4 v, float scale) {
    unsigned b0 = (unsigned char)quant1(v.x, scale);
    unsigned b1 = (unsigned char)quant1(v.y, scale);
    unsigned b2 = (unsigned char)quant1(v.z, scale);
    unsigned b3 = (unsigned char)quant1(v.w, scale);
    return b0 | (b1 << 8) | (b2 << 16) | (b3 << 24);
}

// Tiled fragment-major layout for 16x16x64 i8 MFMA:
// chunk(tile, kt) = 16 KB = 16 granules of 1 KB (granule = one 16-row x 64-kbyte frag).
// Within granule, byte position lane*16 holds {row = lane&15, kbytes (lane>>4)*16..+15}
// -> GEMM ds_read = base + lane*16 (lane-contiguous, conflict-free), staging = linear.

// ---------------- lhs: per-row absmax quantize -> tiled qA_t ----------------
__global__ __launch_bounds__(256) void k_quant_lhs(const float* __restrict__ x,
                                                   int8_t* __restrict__ qt,
                                                   float* __restrict__ s) {
    const int row = blockIdx.x;
    const int t = threadIdx.x;
    const float4* xr = (const float4*)(x + (size_t)row * K_TOT);
    float4 v[4];
    float m = 0.0f;
#pragma unroll
    for (int i = 0; i < 4; ++i) {
        v[i] = xr[t * 4 + i];   // thread owns k-elems 16t .. 16t+15
        m = fmaxf(m, fmaxf(fmaxf(fabsf(v[i].x), fabsf(v[i].y)),
                           fmaxf(fabsf(v[i].z), fabsf(v[i].w))));
    }
#pragma unroll
    for (int off = 32; off; off >>= 1) m = fmaxf(m, __shfl_xor(m, off));
    __shared__ float wmax[4];
    if ((t & 63) == 0) wmax[t >> 6] = m;
    __syncthreads();
    m = fmaxf(fmaxf(wmax[0], wmax[1]), fmaxf(wmax[2], wmax[3]));
    const float scale = fix_scale(m / 127.0f);
    if (t == 0) s[row] = scale;

    v4i w;
#pragma unroll
    for (int i = 0; i < 4; ++i) w[i] = (int)pack4(v[i], scale);

    const int mt = row >> 8, fg = (row >> 4) & 15, r = row & 15;
    const int kt = t >> 2, kb = t & 3;
    const size_t gidx = ((size_t)(mt * 64 + kt) * 16 + fg) * 64 + kb * 16 + r;
    ((v4i*)qt)[gidx] = w;
}

// ---------------- rhs: per-column absmax (atomicMax on float bits) ----------------
__global__ __launch_bounds__(256) void k_rhs_absmax(const float* __restrict__ rhs,
                                                    unsigned* __restrict__ amax) {
    const int f = blockIdx.x * 256 + threadIdx.x;
    const int d0 = blockIdx.y * 256;
    const float* p = rhs + (size_t)d0 * N_TOT + f;
    float m = 0.0f;
#pragma unroll 4
    for (int d = 0; d < 256; ++d)
        m = fmaxf(m, fabsf(p[(size_t)d * N_TOT]));
    atomicMax(amax + f, __float_as_uint(m));
}

// ------- rhs: quantize + transpose -> tiled qB_t (scale fused; writes sB at y==0) -------
__global__ __launch_bounds__(256) void k_quant_rhs_t(const float* __restrict__ rhs,
                                                     const unsigned* __restrict__ amax,
                                                     float* __restrict__ sB,
                                                     int8_t* __restrict__ qt) {
    const int f0 = blockIdx.x * 64;   // col base (multiple of 64)
    const int d0 = blockIdx.y * 64;   // k base
    const int t = threadIdx.x;
    __shared__ float sc[64];
    __shared__ alignas(16) int8_t tile[64][64];  // [col local][k local]
    if (t < 64) {
        const float scale = fix_scale(__uint_as_float(amax[f0 + t]) / 127.0f);
        sc[t] = scale;
        if (blockIdx.y == 0) sB[f0 + t] = scale;
    }
    __syncthreads();
    const int fl = (t & 15) * 4;
    const int rl = t >> 4;
#pragma unroll
    for (int i = 0; i < 4; ++i) {
        const int dl = i * 16 + rl;
        float4 v = *(const float4*)(rhs + (size_t)(d0 + dl) * N_TOT + f0 + fl);
        tile[fl + 0][dl] = quant1(v.x, sc[fl + 0]);
        tile[fl + 1][dl] = quant1(v.y, sc[fl + 1]);
        tile[fl + 2][dl] = quant1(v.z, sc[fl + 2]);
        tile[fl + 3][dl] = quant1(v.w, sc[fl + 3]);
    }
    __syncthreads();
    const int cl = t >> 2, kb = t & 3;
    const int col = f0 + cl;
    const int nt = col >> 8, fg = (col >> 4) & 15, r = col & 15;
    const int kt = d0 >> 6;
    const size_t gidx = ((size_t)(nt * 64 + kt) * 16 + fg) * 64 + kb * 16 + r;
    ((v4i*)qt)[gidx] = *(const v4i*)&tile[cl][kb * 16];
}

// ---- int8 GEMM: 256x256, 8 waves of 128x64 (16x16x64 MFMA), m201 4-phase/2kt ----
#define BM 256
#define BN 256
#define BK 64
#define NKT (K_TOT / BK)   // 64

#define MFMA16(A, B, Cc) __builtin_amdgcn_mfma_i32_16x16x64_i8((A), (B), (Cc), 0, 0, 0)

__global__ __launch_bounds__(512, 2) void k_gemm(const int8_t* __restrict__ qA,   // tiled
                                                 const int8_t* __restrict__ qB,   // tiled
                                                 const float* __restrict__ sA,
                                                 const float* __restrict__ sB,
                                                 float* __restrict__ C) {
    // 4-deep buffer (m201 size): per K-tile chunk = A 16KB + B 16KB
    __shared__ alignas(1024) int8_t lds[4][32768];   // 128 KB -> 1 block/CU, 2 waves/SIMD

    // supercolumn raster: 2 bn-tiles wide (verified FETCH ~394 MB)
    const int bid = blockIdx.x;          // 0..2047
    const int scc = bid >> 6;            // 32 supercolumns
    const int ii = bid & 63;
    const int mt = ii & 31;
    const int ntile = (scc << 1) | (ii >> 5);
    const int bm0 = mt << 8;
    const int bn0 = ntile << 8;

    const int tid = threadIdx.x;         // 0..511
    const int wave = tid >> 6;
    const int lane = tid & 63;
    const int wm = (wave >> 2) * 128;    // 2 wave-rows, 8 m-frags each
    const int wn = (wave & 3) * 64;      // 4 wave-cols, 4 n-frags each

    const int8_t* aBase = qA + (size_t)mt * (64 * 16384);
    const int8_t* bBase = qB + (size_t)ntile * (64 * 16384);

    const int aoff = (wave >> 2) * 8192 + lane * 16;          // + f*1024 (f=0..7)
    const int boff = 16384 + (wave & 3) * 4096 + lane * 16;   // + n*1024 (n=0..3)

    v4i acc[8][4];
#pragma unroll
    for (int f = 0; f < 8; ++f)
#pragma unroll
        for (int n = 0; n < 4; ++n) {
            v4i z = {0, 0, 0, 0};
            acc[f][n] = z;
        }

    // stage one 8KB half-tile: h=0,1 -> A halves; h=2,3 -> B halves (1 gload/thread)
    auto stage_half = [&](int kt, int h) {
        const int b = kt & 3;
        const int8_t* src = (h < 2) ? (aBase + (size_t)kt * 16384 + h * 8192 + tid * 16)
                                    : (bBase + (size_t)kt * 16384 + (h - 2) * 8192 + tid * 16);
        gload_lds16(src, &lds[b][h * 8192 + tid * 16]);
    };

    // prologue: stage kt0 (4 halves) + kt1 (4); wait kt0 done, keep kt1 in flight
    stage_half(0, 0); stage_half(0, 1); stage_half(0, 2); stage_half(0, 3);
    stage_half(1, 0); stage_half(1, 1); stage_half(1, 2); stage_half(1, 3);
    asm volatile("s_waitcnt vmcnt(4)" ::: "memory");
    __builtin_amdgcn_s_barrier();

    for (int kt = 0; kt < NKT; kt += 2) {
        const int8_t* a0 = &lds[kt & 3][0];
        const int8_t* a1 = &lds[(kt + 1) & 3][0];
        const bool st = (kt + 2 < NKT);
        v4i A[8], B[4];

        // ======== P0: kt, m-half 0 (A f0-3 x B n0-3); stage A(kt+2) ========
#pragma unroll
        for (int f = 0; f < 4; ++f) A[f] = *(const v4i*)(a0 + aoff + f * 1024);
#pragma unroll
        for (int n = 0; n < 4; ++n) B[n] = *(const v4i*)(a0 + boff + n * 1024);
        if (st) { stage_half(kt + 2, 0); stage_half(kt + 2, 1); }
        __builtin_amdgcn_s_barrier();
        asm volatile("s_waitcnt lgkmcnt(0)" ::: "memory");
        __builtin_amdgcn_s_setprio(1);
#pragma unroll
        for (int f = 0; f < 4; ++f)
#pragma unroll
            for (int n = 0; n < 4; ++n)
                acc[f][n] = MFMA16(A[f], B[n], acc[f][n]);
        __builtin_amdgcn_s_setprio(0);
        __builtin_amdgcn_s_barrier();

        // ======== P1: kt, m-half 1 (A f4-7 x B n0-3); stage B(kt+2) ========
#pragma unroll
        for (int f = 0; f < 4; ++f) A[4 + f] = *(const v4i*)(a0 + aoff + (4 + f) * 1024);
        if (st) { stage_half(kt + 2, 2); stage_half(kt + 2, 3); }
        __builtin_amdgcn_s_barrier();
        asm volatile("s_waitcnt lgkmcnt(0)" ::: "memory");
        __builtin_amdgcn_s_setprio(1);
#pragma unroll
        for (int f = 0; f < 4; ++f)
#pragma unroll
            for (int n = 0; n < 4; ++n)
                acc[4 + f][n] = MFMA16(A[4 + f], B[n], acc[4 + f][n]);
        __builtin_amdgcn_s_setprio(0);
        // counted: kt+1's 4 loads must complete (P2 reads them); kt+2's stay in flight
        if (st) asm volatile("s_waitcnt vmcnt(4)" ::: "memory");
        else    asm volatile("s_waitcnt vmcnt(0)" ::: "memory");
        __builtin_amdgcn_s_barrier();

        // ======== P2: kt+1, m-half 0; stage A(kt+3) ========
#pragma unroll
        for (int f = 0; f < 4; ++f) A[f] = *(const v4i*)(a1 + aoff + f * 1024);
#pragma unroll
        for (int n = 0; n < 4; ++n) B[n] = *(const v4i*)(a1 + boff + n * 1024);
        if (st) { stage_half(kt + 3, 0); stage_half(kt + 3, 1); }
        __builtin_amdgcn_s_barrier();
        asm volatile("s_waitcnt lgkmcnt(0)" ::: "memory");
        __builtin_amdgcn_s_setprio(1);
#pragma unroll
        for (int f = 0; f < 4; ++f)
#pragma unroll
            for (int n = 0; n < 4; ++n)
                acc[f][n] = MFMA16(A[f], B[n], acc[f][n]);
        __builtin_amdgcn_s_setprio(0);
        __builtin_amdgcn_s_barrier();

        // ======== P3: kt+1, m-half 1; stage B(kt+3); counted vmcnt ========
#pragma unroll
        for (int f = 0; f < 4; ++f) A[4 + f] = *(const v4i*)(a1 + aoff + (4 + f) * 1024);
        if (st) { stage_half(kt + 3, 2); stage_half(kt + 3, 3); }
        __builtin_amdgcn_s_barrier();
        asm volatile("s_waitcnt lgkmcnt(0)" ::: "memory");
        __builtin_amdgcn_s_setprio(1);
#pragma unroll
        for (int f = 0; f < 4; ++f)
#pragma unroll
            for (int n = 0; n < 4; ++n)
                acc[4 + f][n] = MFMA16(A[4 + f], B[n], acc[4 + f][n]);
        __builtin_amdgcn_s_setprio(0);
        // next iter's P0 reads kt+2: its 4 loads must complete; kt+3's stay in flight
        if (st) asm volatile("s_waitcnt vmcnt(4)" ::: "memory");
        __builtin_amdgcn_s_barrier();
    }

    // epilogue: dequant + store. 16x16 C/D: col = lane&15, row = (lane>>4)*4 + reg
    const int cc0 = lane & 15;
    const int rbase = (lane >> 4) * 4;
#pragma unroll
    for (int f = 0; f < 8; ++f) {
        const int gr0 = bm0 + wm + f * 16 + rbase;
        float sa[4];
#pragma unroll
        for (int r = 0; r < 4; ++r) sa[r] = sA[gr0 + r];
#pragma unroll
        for (int n = 0; n < 4; ++n) {
            const int gc = bn0 + wn + n * 16 + cc0;
            const float sb = sB[gc];
#pragma unroll
            for (int r = 0; r < 4; ++r)
                C[(size_t)(gr0 + r) * N_TOT + gc] = (float)acc[f][n][r] * sa[r] * sb;
        }
    }
}

extern "C" void kernel_launch(void* const* d_in, const int* in_sizes, int n_in,
                              void* d_out, int out_size, void* d_ws, size_t ws_size,
                              hipStream_t stream) {
    const float* lhs = (const float*)d_in[0];
    const float* rhs = (const float*)d_in[1];
    float* out = (float*)d_out;
    char* ws = (char*)d_ws;

    int8_t* qA = (int8_t*)ws;                                   // 32 MB (tiled)
    int8_t* qB = (int8_t*)(ws + (size_t)33554432);              // 64 MB (tiled)
    float* sA = (float*)(ws + (size_t)33554432 + 67108864);     // 32 KB
    float* sB = sA + M_TOT;                                     // 64 KB
    unsigned* amax = (unsigned*)(sB + N_TOT);                   // 64 KB

    hipMemsetAsync(amax, 0, N_TOT * sizeof(unsigned), stream);

    k_quant_lhs<<<M_TOT, 256, 0, stream>>>(lhs, qA, sA);
    k_rhs_absmax<<<dim3(N_TOT / 256, K_TOT / 256), 256, 0, stream>>>(rhs, amax);
    k_quant_rhs_t<<<dim3(N_TOT / 64, K_TOT / 64), 256, 0, stream>>>(rhs, amax, sB, qB);
    k_gemm<<<(M_TOT / BM) * (N_TOT / BN), 512, 0, stream>>>(qA, qB, sA, sB, out);
}